// Round 13
// baseline (607.097 us; speedup 1.0000x reference)
//
#include <hip/hip_runtime.h>
#include <hip/hip_bf16.h>

// RCNN: bidirectional simple-RNN + conv1x1 + global max pool + dense sigmoid
// B=256 T=512 V=50000 E=128 H=256 C=128
//
// Round-13 = R12 (measured 606.2 us, best) + depth-2 embxw pipeline +
// paired e_cur gathers. rnn/convpool/prep/dense unchanged.
//  - x[B*T][640] bf16 rows: [0,256) xw_f->h_f units, [256,384) e_cur units
//    (q-half split), [384,640) xw_b->h_b units. rnn overwrites xw with h in
//    place (same block, race-free).
//  - rnn: R4 config (32 blocks = 16 btiles x 2 dirs, 8 waves x 32 cols,
//    2 same-chain waves/SIMD, C-seeded MFMA, T-unroll x2, prefetch-4,
//    LDS-only barrier) — measured 373 us = structural floor (per-step
//    1755 cyc = DS 768 + MFMA 620 + epilogue/barrier; R3/R5/R6/R8/R9/R11
//    all probed alternatives and measured worse).
//  - embxw: 8-t blocks, all idx up front, emb gathers software-pipelined
//    TWO t ahead (depth-1 covered only ~300 of ~600 cyc gather latency).
//  - convpool: R7 verbatim (LDS-staged x rows, 20-kt GEMM, tanh after max).

#define B_ 256
#define T_ 512
#define E_ 128
#define H_ 256
#define C_ 128

typedef __attribute__((ext_vector_type(8))) short short8;
typedef __attribute__((ext_vector_type(4))) float float4v;
typedef __attribute__((ext_vector_type(2))) unsigned int uint2v;

__device__ inline unsigned short f2bf(float f) {
  unsigned u = __float_as_uint(f);
  u += 0x7fffu + ((u >> 16) & 1u);  // RNE
  return (unsigned short)(u >> 16);
}
__device__ inline unsigned pkbf(float a, float b) {
  __hip_bfloat162 h2 = __float22bfloat162_rn(float2{a, b});
  union { __hip_bfloat162 h; unsigned u; } cv;
  cv.h = h2;
  return cv.u;
}
__device__ inline float lo16f(unsigned u) { return __uint_as_float(u << 16); }
__device__ inline float hi16f(unsigned u) { return __uint_as_float(u & 0xffff0000u); }
__device__ inline float fast_tanh(float x) {
  float e = __expf(2.f * x);                 // inf ok -> 1
  float r = __builtin_amdgcn_rcpf(e + 1.f);
  return __builtin_fmaf(-2.f, r, 1.f);
}
__device__ inline unsigned enc_f(float f) {
  unsigned u = __float_as_uint(f);
  return (u & 0x80000000u) ? ~u : (u | 0x80000000u);
}
__device__ inline float dec_f(unsigned key) {
  unsigned bits = (key & 0x80000000u) ? (key ^ 0x80000000u) : ~key;
  return __uint_as_float(bits);
}
__device__ inline void sync_lds() {
  asm volatile("s_waitcnt lgkmcnt(0)\n\ts_barrier" ::: "memory");
}

// ---------------------------------------------------------------------------
// prep: WfT/WbT:[256][128] WcT:[128][640] UfT/UbT:[256][256] (all [n][k]).
// Coalesced reads, strided writes. Also zero-inits pooled (replaces memset).
// ---------------------------------------------------------------------------
__global__ __launch_bounds__(256) void prep_kernel(
    const float* __restrict__ Wf, const float* __restrict__ Wb,
    const float* __restrict__ Wc, const float* __restrict__ Uf,
    const float* __restrict__ Ub,
    unsigned short* __restrict__ WfT, unsigned short* __restrict__ WbT,
    unsigned short* __restrict__ WcT, unsigned short* __restrict__ UfT,
    unsigned short* __restrict__ UbT, unsigned int* __restrict__ pooled) {
  int gid = blockIdx.x * 256 + threadIdx.x;
  int stride = gridDim.x * 256;
  for (int i = gid; i < 128 * 256; i += stride) {  // Wf/Wb [128][256]
    int k = i >> 8, n = i & 255;
    WfT[n * 128 + k] = f2bf(Wf[i]);
    WbT[n * 128 + k] = f2bf(Wb[i]);
  }
  for (int i = gid; i < 640 * 128; i += stride) {  // Wc [640][128]
    int k = i >> 7, n = i & 127;
    WcT[n * 640 + k] = f2bf(Wc[i]);
  }
  for (int i = gid; i < 256 * 256; i += stride) {  // Uf/Ub [256][256]
    int k = i >> 8, n = i & 255;
    UfT[n * 256 + k] = f2bf(Uf[i]);
    UbT[n * 256 + k] = f2bf(Ub[i]);
  }
  for (int i = gid; i < B_ * C_; i += stride) pooled[i] = 0u;
}

// ---------------------------------------------------------------------------
// embxw: dirs 0/1: xw^T = W^T e^T + b, packed units into x; dir 2: e_cur
// gather into q-half-split units [256,384). grid (64 t-octs, 16 btiles, 3),
// 256 thr. emb gathers software-pipelined TWO t ahead.
// ---------------------------------------------------------------------------
__global__ __launch_bounds__(256) void embxw_kernel(
    const int* __restrict__ idxL, const int* __restrict__ idxR,
    const int* __restrict__ idxC, const float* __restrict__ emb,
    const unsigned short* __restrict__ WfT, const unsigned short* __restrict__ WbT,
    const float* __restrict__ bfv, const float* __restrict__ bbv,
    unsigned short* __restrict__ x) {
  const int dir = blockIdx.z;
  const int t0 = blockIdx.x * 8;
  const int b0 = blockIdx.y * 16;
  const int tid = threadIdx.x;
  const int w = tid >> 6, lane = tid & 63, q = lane >> 4, l15 = lane & 15;

  if (dir == 2) {  // e_cur gather: wave w covers t0+2w, t0+2w+1 (paired MLP)
    const int tA = t0 + 2 * w, tB = tA + 1;
    const int erA = idxC[(b0 + l15) * T_ + tA];
    const int erB = idxC[(b0 + l15) * T_ + tB];
    const float* epA = emb + (size_t)erA * E_;
    const float* epB = emb + (size_t)erB * E_;
    float4v ga[8], gb[8];
#pragma unroll
    for (int u = 0; u < 8; ++u) ga[u] = *(const float4v*)(epA + 16 * u + 4 * q);
#pragma unroll
    for (int u = 0; u < 8; ++u) gb[u] = *(const float4v*)(epB + 16 * u + 4 * q);
#pragma unroll
    for (int u = 0; u < 8; ++u) {
      uint2v pk = {pkbf(ga[u][0], ga[u][1]), pkbf(ga[u][2], ga[u][3])};
      int row = b0 + u + 8 * (q >> 1);
      *(uint2v*)(x + ((size_t)row * T_ + tA) * 640 + 256 + 64 * (q & 1) +
                 4 * l15) = pk;
    }
#pragma unroll
    for (int u = 0; u < 8; ++u) {
      uint2v pk = {pkbf(gb[u][0], gb[u][1]), pkbf(gb[u][2], gb[u][3])};
      int row = b0 + u + 8 * (q >> 1);
      *(uint2v*)(x + ((size_t)row * T_ + tB) * 640 + 256 + 64 * (q & 1) +
                 4 * l15) = pk;
    }
    return;
  }

  const int* __restrict__ idx = dir ? idxR : idxL;
  const unsigned short* __restrict__ WT = dir ? WbT : WfT;
  const float* __restrict__ bias = dir ? bbv : bfv;

  short8 wfr[4][4];
#pragma unroll
  for (int mt = 0; mt < 4; ++mt)
#pragma unroll
    for (int kt = 0; kt < 4; ++kt)
      wfr[mt][kt] = *(const short8*)(WT + (64 * w + 16 * mt + l15) * 128 +
                                     kt * 32 + q * 8);
  float4v bv[4];
#pragma unroll
  for (int mt = 0; mt < 4; ++mt)
    bv[mt] = *(const float4v*)(bias + 64 * w + 16 * mt + 4 * q);

  // all 8 idx up front
  int er[8];
#pragma unroll
  for (int j = 0; j < 8; ++j) er[j] = idx[(b0 + l15) * T_ + t0 + j];

  // prologue gathers for j=0 and j=1 (pipeline depth 2)
  float4v g0[8], g1[8];
#pragma unroll
  for (int kt = 0; kt < 4; ++kt) {
    const float* p8 = emb + (size_t)er[0] * E_ + kt * 32 + q * 8;
    g0[2 * kt] = *(const float4v*)p8;
    g0[2 * kt + 1] = *(const float4v*)(p8 + 4);
  }
#pragma unroll
  for (int kt = 0; kt < 4; ++kt) {
    const float* p8 = emb + (size_t)er[1] * E_ + kt * 32 + q * 8;
    g1[2 * kt] = *(const float4v*)p8;
    g1[2 * kt + 1] = *(const float4v*)(p8 + 4);
  }

#pragma unroll 1
  for (int j = 0; j < 8; ++j) {
    float4v g2[8];
    if (j < 6) {  // prefetch t+2's emb row — two loop bodies cover latency
#pragma unroll
      for (int kt = 0; kt < 4; ++kt) {
        const float* p8 = emb + (size_t)er[j + 2] * E_ + kt * 32 + q * 8;
        g2[2 * kt] = *(const float4v*)p8;
        g2[2 * kt + 1] = *(const float4v*)(p8 + 4);
      }
    }
    short8 efr[4];
#pragma unroll
    for (int kt = 0; kt < 4; ++kt) {
      union { unsigned u[4]; short8 s; } cv;
      cv.u[0] = pkbf(g0[2 * kt][0], g0[2 * kt][1]);
      cv.u[1] = pkbf(g0[2 * kt][2], g0[2 * kt][3]);
      cv.u[2] = pkbf(g0[2 * kt + 1][0], g0[2 * kt + 1][1]);
      cv.u[3] = pkbf(g0[2 * kt + 1][2], g0[2 * kt + 1][3]);
      efr[kt] = cv.s;
    }
    float4v acc[4];
#pragma unroll
    for (int mt = 0; mt < 4; ++mt) acc[mt] = (float4v){0.f, 0.f, 0.f, 0.f};
#pragma unroll
    for (int kt = 0; kt < 4; ++kt)
#pragma unroll
      for (int mt = 0; mt < 4; ++mt)
        acc[mt] = __builtin_amdgcn_mfma_f32_16x16x32_bf16(wfr[mt][kt], efr[kt],
                                                          acc[mt], 0, 0, 0);
    const int t = t0 + j;
#pragma unroll
    for (int mt = 0; mt < 4; ++mt) {
      float4v v = acc[mt] + bv[mt];
      uint2v pk = {pkbf(v[0], v[1]), pkbf(v[2], v[3])};
      *(uint2v*)(x + ((size_t)(b0 + 4 * w + mt) * T_ + t) * 640 + dir * 384 +
                 lane * 4) = pk;
    }
#pragma unroll
    for (int kk = 0; kk < 8; ++kk) {
      g0[kk] = g1[kk];
      if (j < 6) g1[kk] = g2[kk];
    }
  }
}

// ---------------------------------------------------------------------------
// rnn: h_t = tanh(U^T h ; C-seed = xw_t). One chain per block, 8 waves x
// 32 cols (2 same-chain waves/SIMD). 32 blocks. Unroll x2, prefetch 4.
// R4 configuration — measured 373 us (structural floor).
// ---------------------------------------------------------------------------
__global__ __launch_bounds__(512, 2) void rnn_kernel(
    unsigned short* x, const unsigned short* __restrict__ UfT,
    const unsigned short* __restrict__ UbT) {
  const int dir = blockIdx.x & 1;
  const int b0 = (blockIdx.x >> 1) * 16;
  const unsigned short* __restrict__ UT = dir ? UbT : UfT;
  const int xoff = dir ? 384 : 0;
  const int tstep = dir ? -1 : 1;
  const int t0 = dir ? (T_ - 1) : 0;
  const ptrdiff_t dstep = (ptrdiff_t)tstep * 640;  // shorts per t-step

  const int tid = threadIdx.x;
  const int wv = tid >> 6, lane = tid & 63, q = lane >> 4, l15 = lane & 15;

  // stride 280 shorts: b128 bank-start 4*(3*l15+q)%32 -> 2-way (free)
  __shared__ __attribute__((aligned(16))) unsigned short hbuf[2][16][280];
  unsigned short* hb0 = &hbuf[0][0][0];
  unsigned short* hb1 = &hbuf[1][0][0];

  for (int i = tid; i < 16 * 280; i += 512) hb0[i] = 0;

  short8 ufr[2][8];
#pragma unroll
  for (int mt = 0; mt < 2; ++mt)
#pragma unroll
    for (int kt = 0; kt < 8; ++kt)
      ufr[mt][kt] = *(const short8*)(UT + (32 * wv + 16 * mt + l15) * H_ +
                                     kt * 32 + q * 8);

  unsigned short* ptrS[2];        // store slot (step t of current pair)
  const unsigned short* ptrL[2];  // load slot (t + 4*tstep)
  uint2v curA[2], curB[2], infA[2], infB[2];
#pragma unroll
  for (int mt = 0; mt < 2; ++mt) {
    unsigned short* base =
        x + (size_t)(b0 + 2 * wv + mt) * T_ * 640 + xoff + lane * 4;
    unsigned short* bt = base + (ptrdiff_t)t0 * 640;
    curA[mt] = *(const uint2v*)(bt);
    curB[mt] = *(const uint2v*)(bt + dstep);
    infA[mt] = *(const uint2v*)(bt + 2 * dstep);
    infB[mt] = *(const uint2v*)(bt + 3 * dstep);
    ptrS[mt] = bt;
    ptrL[mt] = bt + 4 * dstep;
  }

  const unsigned lrd = l15 * 280;
  const unsigned lwr = l15 * 280 + 32 * wv;

  __syncthreads();

#pragma unroll 1
  for (int p = 0; p < 256; ++p) {
    uint2v ldA[2], ldB[2];
    if (p < 254) {
#pragma unroll
      for (int mt = 0; mt < 2; ++mt) {
        ldA[mt] = *(const uint2v*)(ptrL[mt]);
        ldB[mt] = *(const uint2v*)(ptrL[mt] + dstep);
      }
    } else {
#pragma unroll
      for (int mt = 0; mt < 2; ++mt) { ldA[mt] = infA[mt]; ldB[mt] = infB[mt]; }
    }
#pragma unroll
    for (int mt = 0; mt < 2; ++mt) ptrL[mt] += 2 * dstep;

    // ---- STEP A: read hb0, write hb1 ----
    {
      short8 afr[8];
#pragma unroll
      for (int kt = 0; kt < 8; ++kt)
        afr[kt] = *(const short8*)(hb0 + lrd + kt * 32 + q * 8);
      float4v acc[2];
#pragma unroll
      for (int mt = 0; mt < 2; ++mt)
        acc[mt] = (float4v){lo16f(curA[mt].x), hi16f(curA[mt].x),
                            lo16f(curA[mt].y), hi16f(curA[mt].y)};
#pragma unroll
      for (int kt = 0; kt < 8; ++kt)
#pragma unroll
        for (int mt = 0; mt < 2; ++mt)
          acc[mt] = __builtin_amdgcn_mfma_f32_16x16x32_bf16(
              ufr[mt][kt], afr[kt], acc[mt], 0, 0, 0);
#pragma unroll
      for (int mt = 0; mt < 2; ++mt) {
        uint2v hv = {pkbf(fast_tanh(acc[mt][0]), fast_tanh(acc[mt][1])),
                     pkbf(fast_tanh(acc[mt][2]), fast_tanh(acc[mt][3]))};
        *(uint2v*)(hb1 + lwr + 16 * mt + 4 * q) = hv;
        *(uint2v*)ptrS[mt] = hv;
      }
    }
    sync_lds();

    // ---- STEP B: read hb1, write hb0 ----
    {
      short8 afr[8];
#pragma unroll
      for (int kt = 0; kt < 8; ++kt)
        afr[kt] = *(const short8*)(hb1 + lrd + kt * 32 + q * 8);
      float4v acc[2];
#pragma unroll
      for (int mt = 0; mt < 2; ++mt)
        acc[mt] = (float4v){lo16f(curB[mt].x), hi16f(curB[mt].x),
                            lo16f(curB[mt].y), hi16f(curB[mt].y)};
#pragma unroll
      for (int kt = 0; kt < 8; ++kt)
#pragma unroll
        for (int mt = 0; mt < 2; ++mt)
          acc[mt] = __builtin_amdgcn_mfma_f32_16x16x32_bf16(
              ufr[mt][kt], afr[kt], acc[mt], 0, 0, 0);
#pragma unroll
      for (int mt = 0; mt < 2; ++mt) {
        uint2v hv = {pkbf(fast_tanh(acc[mt][0]), fast_tanh(acc[mt][1])),
                     pkbf(fast_tanh(acc[mt][2]), fast_tanh(acc[mt][3]))};
        *(uint2v*)(hb0 + lwr + 16 * mt + 4 * q) = hv;
        *(uint2v*)(ptrS[mt] + dstep) = hv;
      }
    }
#pragma unroll
    for (int mt = 0; mt < 2; ++mt) {
      ptrS[mt] += 2 * dstep;
      curA[mt] = infA[mt];
      curB[mt] = infB[mt];
      infA[mt] = ldA[mt];
      infB[mt] = ldB[mt];
    }
    sync_lds();
  }
}

// ---------------------------------------------------------------------------
// convpool: out = tanh(max_t(x_row @ Wc) + bc). R7 verbatim.
// grid (16 btiles x 32 tchunks), 256 thr (4 waves x 32 c-cols). LDS dbuf.
// ---------------------------------------------------------------------------
__global__ __launch_bounds__(256, 2) void convpool_kernel(
    const unsigned short* __restrict__ x, const unsigned short* __restrict__ WcT,
    const float* __restrict__ bc, unsigned int* __restrict__ pooled) {
  const int b0 = (blockIdx.x & 15) * 16;
  const int t0 = (blockIdx.x >> 4) * 16;
  const int tid = threadIdx.x;
  const int w = tid >> 6, lane = tid & 63, q = lane >> 4, l15 = lane & 15;

  __shared__ __attribute__((aligned(16))) unsigned short tile[2][16][648];

  short8 wfr[2][20];
#pragma unroll
  for (int ct = 0; ct < 2; ++ct)
#pragma unroll
    for (int kt = 0; kt < 20; ++kt)
      wfr[ct][kt] = *(const short8*)(WcT +
                                     (size_t)(32 * w + 16 * ct + l15) * 640 +
                                     kt * 32 + q * 8);
  float4v bv[2];
#pragma unroll
  for (int ct = 0; ct < 2; ++ct)
    bv[ct] = *(const float4v*)(bc + 32 * w + 16 * ct + 4 * q);

  float4v mx[2];
  mx[0] = (float4v){-1e30f, -1e30f, -1e30f, -1e30f};
  mx[1] = mx[0];

  const int srow = tid >> 4, ssub = tid & 15;
  {
    const unsigned short* src = x + ((size_t)(b0 + srow) * T_ + t0) * 640;
#pragma unroll
    for (int j = 0; j < 5; ++j)
      *(short8*)&tile[0][srow][ssub * 8 + j * 128] =
          *(const short8*)(src + ssub * 8 + j * 128);
  }
  __syncthreads();

#pragma unroll 1
  for (int j = 0; j < 16; ++j) {
    const int t = t0 + j;
    const int buf = j & 1;
    if (j < 15) {
      const unsigned short* src = x + ((size_t)(b0 + srow) * T_ + t + 1) * 640;
#pragma unroll
      for (int jj = 0; jj < 5; ++jj)
        *(short8*)&tile[buf ^ 1][srow][ssub * 8 + jj * 128] =
            *(const short8*)(src + ssub * 8 + jj * 128);
    }
    float4v acc[2];
    acc[0] = (float4v){0.f, 0.f, 0.f, 0.f};
    acc[1] = (float4v){0.f, 0.f, 0.f, 0.f};
#pragma unroll
    for (int kt = 0; kt < 20; ++kt) {
      int row, so1, so2;
      if (kt < 8) {
        row = 2 * kt + (q >> 1);
        so1 = 64 * (2 * (q & 1)) + 4 * l15;
        so2 = so1 + 64;
      } else if (kt < 12) {
        row = 2 * (kt - 8) + (q >> 1) + 8 * (q & 1);
        so1 = 256 + 4 * l15;
        so2 = 320 + 4 * l15;
      } else {
        row = 2 * (kt - 12) + (q >> 1);
        so1 = 384 + 64 * (2 * (q & 1)) + 4 * l15;
        so2 = so1 + 64;
      }
      union { unsigned u[4]; short8 s; } cv;
      uint2v c1 = *(const uint2v*)&tile[buf][row][so1];
      uint2v c2 = *(const uint2v*)&tile[buf][row][so2];
      cv.u[0] = c1.x; cv.u[1] = c1.y; cv.u[2] = c2.x; cv.u[3] = c2.y;
      acc[0] = __builtin_amdgcn_mfma_f32_16x16x32_bf16(wfr[0][kt], cv.s,
                                                       acc[0], 0, 0, 0);
      acc[1] = __builtin_amdgcn_mfma_f32_16x16x32_bf16(wfr[1][kt], cv.s,
                                                       acc[1], 0, 0, 0);
    }
#pragma unroll
    for (int ct = 0; ct < 2; ++ct)
#pragma unroll
      for (int i = 0; i < 4; ++i)
        mx[ct][i] = fmaxf(mx[ct][i], acc[ct][i]);  // pre-activation max
    __syncthreads();
  }
#pragma unroll
  for (int ct = 0; ct < 2; ++ct)
#pragma unroll
    for (int i = 0; i < 4; ++i)
      atomicMax(pooled + (b0 + l15) * C_ + 32 * w + 16 * ct + 4 * q + i,
                enc_f(fast_tanh(mx[ct][i] + bv[ct][i])));
}

// ---------------------------------------------------------------------------
// dense: out = sigmoid(pooled @ Wd + bd)  [256,128]@[128,2]
// ---------------------------------------------------------------------------
__global__ __launch_bounds__(256) void dense_kernel(
    const unsigned int* __restrict__ pooled, const float* __restrict__ Wd,
    const float* __restrict__ bd, float* __restrict__ out) {
  int b = threadIdx.x;
  float s0 = bd[0], s1 = bd[1];
#pragma unroll 4
  for (int c = 0; c < C_; ++c) {
    float f = dec_f(pooled[b * C_ + c]);
    s0 += f * Wd[c * 2 + 0];
    s1 += f * Wd[c * 2 + 1];
  }
  out[b * 2 + 0] = 1.f / (1.f + __expf(-s0));
  out[b * 2 + 1] = 1.f / (1.f + __expf(-s1));
}

// ---------------------------------------------------------------------------
extern "C" void kernel_launch(void* const* d_in, const int* in_sizes, int n_in,
                              void* d_out, int out_size, void* d_ws, size_t ws_size,
                              hipStream_t stream) {
  const int* idxC = (const int*)d_in[0];
  const int* idxL = (const int*)d_in[1];
  const int* idxR = (const int*)d_in[2];
  const float* emb = (const float*)d_in[3];
  const float* Wf = (const float*)d_in[4];
  const float* Uf = (const float*)d_in[5];
  const float* bf_ = (const float*)d_in[6];
  const float* Wb = (const float*)d_in[7];
  const float* Ub = (const float*)d_in[8];
  const float* bb_ = (const float*)d_in[9];
  const float* Wc = (const float*)d_in[10];
  const float* bc = (const float*)d_in[11];
  const float* Wd = (const float*)d_in[12];
  const float* bd = (const float*)d_in[13];

  char* ws = (char*)d_ws;
  unsigned short* x = (unsigned short*)ws;                          // 167,772,160 B
  unsigned int* pooled = (unsigned int*)(ws + 167772160);           //     131,072 B
  unsigned short* WfT = (unsigned short*)(ws + 167772160 + 131072); //      65,536 B
  unsigned short* WbT = WfT + 256 * 128;
  unsigned short* WcT = WbT + 256 * 128;
  unsigned short* UfT = WcT + 128 * 640;
  unsigned short* UbT = UfT + 256 * 256;

  prep_kernel<<<64, 256, 0, stream>>>(Wf, Wb, Wc, Uf, Ub, WfT, WbT, WcT, UfT,
                                      UbT, pooled);
  embxw_kernel<<<dim3(64, 16, 3), 256, 0, stream>>>(idxL, idxR, idxC, emb,
                                                    WfT, WbT, bf_, bb_, x);
  rnn_kernel<<<32, 512, 0, stream>>>(x, UfT, UbT);
  convpool_kernel<<<512, 256, 0, stream>>>(x, WcT, bc, pooled);
  dense_kernel<<<1, 256, 0, stream>>>(pooled, Wd, bd, (float*)d_out);
}

// Round 14
// 589.471 us; speedup vs baseline: 1.0299x; 1.0299x over previous
//
#include <hip/hip_runtime.h>
#include <hip/hip_bf16.h>

// RCNN: bidirectional simple-RNN + conv1x1 + global max pool + dense sigmoid
// B=256 T=512 V=50000 E=128 H=256 C=128
//
// Round-14 = R12/R13 (606 us) + producer-consumer fusion: embxw runs INSIDE
// the rnn launch on the 224 CUs the rnn leaves idle.
//  - fused kernel, grid 1568 x 512 thr, dynamic LDS 120 KB -> 1 block/CU:
//      blocks [0,32):     rnn (R4 body, 373 us floor) + chunk polling
//      blocks [32,1056):  embxw GEMM, z-ordered (z -> fwd chunk z + bwd
//                         chunk 31-z, all btiles) so production order ==
//                         rnn consumption order; publishes per-(dir,btile,
//                         16t-chunk) flags with agent-scope release.
//      blocks [1056,1568): e_cur gather (not needed by rnn; no flags).
//    rnn acquires each flag (relaxed spin + s_sleep, one acquire load)
//    before prefetching into a new 16-t chunk. Flags zeroed by prep every
//    launch. Liveness: producers never wait; all blocks co-residency not
//    required. 1 block/CU isolates rnn pipes from embxw work.
//  - convpool/dense: R7/R13 verbatim (separate kernels, stream-ordered).

#define B_ 256
#define T_ 512
#define E_ 128
#define H_ 256
#define C_ 128

typedef __attribute__((ext_vector_type(8))) short short8;
typedef __attribute__((ext_vector_type(4))) float float4v;
typedef __attribute__((ext_vector_type(2))) unsigned int uint2v;

__device__ inline unsigned short f2bf(float f) {
  unsigned u = __float_as_uint(f);
  u += 0x7fffu + ((u >> 16) & 1u);  // RNE
  return (unsigned short)(u >> 16);
}
__device__ inline unsigned pkbf(float a, float b) {
  __hip_bfloat162 h2 = __float22bfloat162_rn(float2{a, b});
  union { __hip_bfloat162 h; unsigned u; } cv;
  cv.h = h2;
  return cv.u;
}
__device__ inline float lo16f(unsigned u) { return __uint_as_float(u << 16); }
__device__ inline float hi16f(unsigned u) { return __uint_as_float(u & 0xffff0000u); }
__device__ inline float fast_tanh(float x) {
  float e = __expf(2.f * x);                 // inf ok -> 1
  float r = __builtin_amdgcn_rcpf(e + 1.f);
  return __builtin_fmaf(-2.f, r, 1.f);
}
__device__ inline unsigned enc_f(float f) {
  unsigned u = __float_as_uint(f);
  return (u & 0x80000000u) ? ~u : (u | 0x80000000u);
}
__device__ inline float dec_f(unsigned key) {
  unsigned bits = (key & 0x80000000u) ? (key ^ 0x80000000u) : ~key;
  return __uint_as_float(bits);
}
__device__ inline void sync_lds() {
  asm volatile("s_waitcnt lgkmcnt(0)\n\ts_barrier" ::: "memory");
}
__device__ inline int clampt(int t) { return t < 0 ? 0 : (t > 511 ? 511 : t); }

__device__ inline void wait_flag(const int* f) {
  if (__hip_atomic_load(f, __ATOMIC_RELAXED, __HIP_MEMORY_SCOPE_AGENT) == 0) {
    while (__hip_atomic_load(f, __ATOMIC_RELAXED, __HIP_MEMORY_SCOPE_AGENT) ==
           0)
      __builtin_amdgcn_s_sleep(8);
  }
  // one acquire load to pull in the producer's data (L1/L2 invalidate)
  (void)__hip_atomic_load(f, __ATOMIC_ACQUIRE, __HIP_MEMORY_SCOPE_AGENT);
}

// ---------------------------------------------------------------------------
// prep: WfT/WbT:[256][128] WcT:[128][640] UfT/UbT:[256][256] (all [n][k]).
// Coalesced reads, strided writes. Zeroes pooled and the 1024 chunk flags.
// ---------------------------------------------------------------------------
__global__ __launch_bounds__(256) void prep_kernel(
    const float* __restrict__ Wf, const float* __restrict__ Wb,
    const float* __restrict__ Wc, const float* __restrict__ Uf,
    const float* __restrict__ Ub,
    unsigned short* __restrict__ WfT, unsigned short* __restrict__ WbT,
    unsigned short* __restrict__ WcT, unsigned short* __restrict__ UfT,
    unsigned short* __restrict__ UbT, unsigned int* __restrict__ pooled,
    int* __restrict__ flags) {
  int gid = blockIdx.x * 256 + threadIdx.x;
  int stride = gridDim.x * 256;
  for (int i = gid; i < 128 * 256; i += stride) {  // Wf/Wb [128][256]
    int k = i >> 8, n = i & 255;
    WfT[n * 128 + k] = f2bf(Wf[i]);
    WbT[n * 128 + k] = f2bf(Wb[i]);
  }
  for (int i = gid; i < 640 * 128; i += stride) {  // Wc [640][128]
    int k = i >> 7, n = i & 127;
    WcT[n * 640 + k] = f2bf(Wc[i]);
  }
  for (int i = gid; i < 256 * 256; i += stride) {  // Uf/Ub [256][256]
    int k = i >> 8, n = i & 255;
    UfT[n * 256 + k] = f2bf(Uf[i]);
    UbT[n * 256 + k] = f2bf(Ub[i]);
  }
  for (int i = gid; i < B_ * C_; i += stride) pooled[i] = 0u;
  for (int i = gid; i < 1024; i += stride) flags[i] = 0;
}

// ---------------------------------------------------------------------------
// fused: rnn (blocks 0-31) + embxw producers (32-1055) + e_cur (1056-1567).
// ---------------------------------------------------------------------------
__global__ __launch_bounds__(512, 1) void fused_kernel(
    const int* __restrict__ idxL, const int* __restrict__ idxR,
    const int* __restrict__ idxC, const float* __restrict__ emb,
    const unsigned short* __restrict__ WfT,
    const unsigned short* __restrict__ WbT,
    const float* __restrict__ bfv, const float* __restrict__ bbv,
    const unsigned short* __restrict__ UfT,
    const unsigned short* __restrict__ UbT, unsigned short* x,
    int* __restrict__ flags) {
  const int blk = blockIdx.x;
  const int tid = threadIdx.x;
  const int lane = tid & 63, q = lane >> 4, l15 = lane & 15;

  __shared__ __attribute__((aligned(16))) unsigned short hbuf[2][16][280];

  if (blk < 32) {
    // ======================= RNN (R4 body + polls) =======================
    const int dir = blk & 1;
    const int btile = blk >> 1;
    const int b0 = btile * 16;
    const unsigned short* __restrict__ UT = dir ? UbT : UfT;
    const int xoff = dir ? 384 : 0;
    const int tstep = dir ? -1 : 1;
    const int t0 = dir ? (T_ - 1) : 0;
    const ptrdiff_t dstep = (ptrdiff_t)tstep * 640;
    const int wv = tid >> 6;
    const int* fl = flags + (dir * 16 + btile) * 32;

    unsigned short* hb0 = &hbuf[0][0][0];
    unsigned short* hb1 = &hbuf[1][0][0];
    for (int i = tid; i < 16 * 280; i += 512) hb0[i] = 0;

    short8 ufr[2][8];
#pragma unroll
    for (int mt = 0; mt < 2; ++mt)
#pragma unroll
      for (int kt = 0; kt < 8; ++kt)
        ufr[mt][kt] = *(const short8*)(UT + (32 * wv + 16 * mt + l15) * H_ +
                                       kt * 32 + q * 8);

    int lastc = dir ? 31 : 0;
    wait_flag(fl + lastc);  // covers prologue reads t0..t0+3

    unsigned short* ptrS[2];
    const unsigned short* ptrL[2];
    uint2v curA[2], curB[2], infA[2], infB[2];
#pragma unroll
    for (int mt = 0; mt < 2; ++mt) {
      unsigned short* base =
          x + (size_t)(b0 + 2 * wv + mt) * T_ * 640 + xoff + lane * 4;
      unsigned short* bt = base + (ptrdiff_t)t0 * 640;
      curA[mt] = *(const uint2v*)(bt);
      curB[mt] = *(const uint2v*)(bt + dstep);
      infA[mt] = *(const uint2v*)(bt + 2 * dstep);
      infB[mt] = *(const uint2v*)(bt + 3 * dstep);
      ptrS[mt] = bt;
      ptrL[mt] = bt + 4 * dstep;
    }

    const unsigned lrd = l15 * 280;
    const unsigned lwr = l15 * 280 + 32 * wv;

    __syncthreads();

#pragma unroll 1
    for (int p = 0; p < 256; ++p) {
      // flag for the chunk the prefetch (t +4/+5) touches
      int c = dir ? ((506 - 2 * p) >> 4) : ((2 * p + 5) >> 4);
      c = c < 0 ? 0 : (c > 31 ? 31 : c);
      if (c != lastc) {
        wait_flag(fl + c);
        lastc = c;
      }
      uint2v ldA[2], ldB[2];
      if (p < 254) {
#pragma unroll
        for (int mt = 0; mt < 2; ++mt) {
          ldA[mt] = *(const uint2v*)(ptrL[mt]);
          ldB[mt] = *(const uint2v*)(ptrL[mt] + dstep);
        }
      } else {
#pragma unroll
        for (int mt = 0; mt < 2; ++mt) {
          ldA[mt] = infA[mt];
          ldB[mt] = infB[mt];
        }
      }
#pragma unroll
      for (int mt = 0; mt < 2; ++mt) ptrL[mt] += 2 * dstep;

      // ---- STEP A: read hb0, write hb1 ----
      {
        short8 afr[8];
#pragma unroll
        for (int kt = 0; kt < 8; ++kt)
          afr[kt] = *(const short8*)(hb0 + lrd + kt * 32 + q * 8);
        float4v acc[2];
#pragma unroll
        for (int mt = 0; mt < 2; ++mt)
          acc[mt] = (float4v){lo16f(curA[mt].x), hi16f(curA[mt].x),
                              lo16f(curA[mt].y), hi16f(curA[mt].y)};
#pragma unroll
        for (int kt = 0; kt < 8; ++kt)
#pragma unroll
          for (int mt = 0; mt < 2; ++mt)
            acc[mt] = __builtin_amdgcn_mfma_f32_16x16x32_bf16(
                ufr[mt][kt], afr[kt], acc[mt], 0, 0, 0);
#pragma unroll
        for (int mt = 0; mt < 2; ++mt) {
          uint2v hv = {pkbf(fast_tanh(acc[mt][0]), fast_tanh(acc[mt][1])),
                       pkbf(fast_tanh(acc[mt][2]), fast_tanh(acc[mt][3]))};
          *(uint2v*)(hb1 + lwr + 16 * mt + 4 * q) = hv;
          *(uint2v*)ptrS[mt] = hv;
        }
      }
      sync_lds();

      // ---- STEP B: read hb1, write hb0 ----
      {
        short8 afr[8];
#pragma unroll
        for (int kt = 0; kt < 8; ++kt)
          afr[kt] = *(const short8*)(hb1 + lrd + kt * 32 + q * 8);
        float4v acc[2];
#pragma unroll
        for (int mt = 0; mt < 2; ++mt)
          acc[mt] = (float4v){lo16f(curB[mt].x), hi16f(curB[mt].x),
                              lo16f(curB[mt].y), hi16f(curB[mt].y)};
#pragma unroll
        for (int kt = 0; kt < 8; ++kt)
#pragma unroll
          for (int mt = 0; mt < 2; ++mt)
            acc[mt] = __builtin_amdgcn_mfma_f32_16x16x32_bf16(
                ufr[mt][kt], afr[kt], acc[mt], 0, 0, 0);
#pragma unroll
        for (int mt = 0; mt < 2; ++mt) {
          uint2v hv = {pkbf(fast_tanh(acc[mt][0]), fast_tanh(acc[mt][1])),
                       pkbf(fast_tanh(acc[mt][2]), fast_tanh(acc[mt][3]))};
          *(uint2v*)(hb0 + lwr + 16 * mt + 4 * q) = hv;
          *(uint2v*)(ptrS[mt] + dstep) = hv;
        }
      }
#pragma unroll
      for (int mt = 0; mt < 2; ++mt) {
        ptrS[mt] += 2 * dstep;
        curA[mt] = infA[mt];
        curB[mt] = infB[mt];
        infA[mt] = ldA[mt];
        infB[mt] = ldB[mt];
      }
      sync_lds();
    }
    return;
  }

  if (blk < 1056) {
    // ==================== embxw GEMM producer ====================
    const int b2 = blk - 32;
    const int z = b2 >> 5, r = b2 & 31;
    const int btile = r & 15, dirg = r >> 4;
    const int chunk = dirg ? (31 - z) : z;
    const int w8 = tid >> 6;           // 0..7
    const int g = w8 >> 2, wv = w8 & 3;
    const int t0 = chunk * 16 + g * 8;  // this wave-group's 8 t
    const int b0 = btile * 16;
    const int* __restrict__ idx = dirg ? idxR : idxL;
    const unsigned short* __restrict__ WT = dirg ? WbT : WfT;
    const float* __restrict__ bias = dirg ? bbv : bfv;

    short8 wfr[4][4];
#pragma unroll
    for (int mt = 0; mt < 4; ++mt)
#pragma unroll
      for (int kt = 0; kt < 4; ++kt)
        wfr[mt][kt] = *(const short8*)(WT + (64 * wv + 16 * mt + l15) * 128 +
                                       kt * 32 + q * 8);
    float4v bv[4];
#pragma unroll
    for (int mt = 0; mt < 4; ++mt)
      bv[mt] = *(const float4v*)(bias + 64 * wv + 16 * mt + 4 * q);

    int er[8];
#pragma unroll
    for (int j = 0; j < 8; ++j) er[j] = idx[(b0 + l15) * T_ + t0 + j];

    float4v g0[8];
#pragma unroll
    for (int kt = 0; kt < 4; ++kt) {
      const float* p8 = emb + (size_t)er[0] * E_ + kt * 32 + q * 8;
      g0[2 * kt] = *(const float4v*)p8;
      g0[2 * kt + 1] = *(const float4v*)(p8 + 4);
    }

#pragma unroll 1
    for (int j = 0; j < 8; ++j) {
      float4v gn[8];
      if (j < 7) {
#pragma unroll
        for (int kt = 0; kt < 4; ++kt) {
          const float* p8 = emb + (size_t)er[j + 1] * E_ + kt * 32 + q * 8;
          gn[2 * kt] = *(const float4v*)p8;
          gn[2 * kt + 1] = *(const float4v*)(p8 + 4);
        }
      }
      short8 efr[4];
#pragma unroll
      for (int kt = 0; kt < 4; ++kt) {
        union { unsigned u[4]; short8 s; } cv;
        cv.u[0] = pkbf(g0[2 * kt][0], g0[2 * kt][1]);
        cv.u[1] = pkbf(g0[2 * kt][2], g0[2 * kt][3]);
        cv.u[2] = pkbf(g0[2 * kt + 1][0], g0[2 * kt + 1][1]);
        cv.u[3] = pkbf(g0[2 * kt + 1][2], g0[2 * kt + 1][3]);
        efr[kt] = cv.s;
      }
      float4v acc[4];
#pragma unroll
      for (int mt = 0; mt < 4; ++mt) acc[mt] = (float4v){0.f, 0.f, 0.f, 0.f};
#pragma unroll
      for (int kt = 0; kt < 4; ++kt)
#pragma unroll
        for (int mt = 0; mt < 4; ++mt)
          acc[mt] = __builtin_amdgcn_mfma_f32_16x16x32_bf16(
              wfr[mt][kt], efr[kt], acc[mt], 0, 0, 0);
      const int t = t0 + j;
#pragma unroll
      for (int mt = 0; mt < 4; ++mt) {
        float4v v = acc[mt] + bv[mt];
        uint2v pk = {pkbf(v[0], v[1]), pkbf(v[2], v[3])};
        *(uint2v*)(x + ((size_t)(b0 + 4 * wv + mt) * T_ + t) * 640 +
                   dirg * 384 + lane * 4) = pk;
      }
      if (j < 7) {
#pragma unroll
        for (int kk = 0; kk < 8; ++kk) g0[kk] = gn[kk];
      }
    }
    __syncthreads();  // drains all waves' stores (vmcnt(0) before barrier)
    if (tid == 0) {
      __threadfence();
      __hip_atomic_store(flags + (dirg * 16 + btile) * 32 + chunk, 1,
                         __ATOMIC_RELEASE, __HIP_MEMORY_SCOPE_AGENT);
    }
    return;
  }

  // ======================== e_cur gather ========================
  {
    const int b3 = blk - 1056;
    const int btile = b3 & 15, tch = b3 >> 4;
    const int b0 = btile * 16;
    const int w8 = tid >> 6;
    const int tA = tch * 16 + 2 * w8, tB = tA + 1;
    const int erA = idxC[(b0 + l15) * T_ + tA];
    const int erB = idxC[(b0 + l15) * T_ + tB];
    const float* epA = emb + (size_t)erA * E_;
    const float* epB = emb + (size_t)erB * E_;
    float4v ga[8], gb[8];
#pragma unroll
    for (int u = 0; u < 8; ++u) ga[u] = *(const float4v*)(epA + 16 * u + 4 * q);
#pragma unroll
    for (int u = 0; u < 8; ++u) gb[u] = *(const float4v*)(epB + 16 * u + 4 * q);
#pragma unroll
    for (int u = 0; u < 8; ++u) {
      uint2v pk = {pkbf(ga[u][0], ga[u][1]), pkbf(ga[u][2], ga[u][3])};
      int row = b0 + u + 8 * (q >> 1);
      *(uint2v*)(x + ((size_t)row * T_ + tA) * 640 + 256 + 64 * (q & 1) +
                 4 * l15) = pk;
    }
#pragma unroll
    for (int u = 0; u < 8; ++u) {
      uint2v pk = {pkbf(gb[u][0], gb[u][1]), pkbf(gb[u][2], gb[u][3])};
      int row = b0 + u + 8 * (q >> 1);
      *(uint2v*)(x + ((size_t)row * T_ + tB) * 640 + 256 + 64 * (q & 1) +
                 4 * l15) = pk;
    }
  }
}

// ---------------------------------------------------------------------------
// convpool: out = tanh(max_t(x_row @ Wc) + bc). R7 verbatim.
// grid (16 btiles x 32 tchunks), 256 thr (4 waves x 32 c-cols). LDS dbuf.
// ---------------------------------------------------------------------------
__global__ __launch_bounds__(256, 2) void convpool_kernel(
    const unsigned short* __restrict__ x, const unsigned short* __restrict__ WcT,
    const float* __restrict__ bc, unsigned int* __restrict__ pooled) {
  const int b0 = (blockIdx.x & 15) * 16;
  const int t0 = (blockIdx.x >> 4) * 16;
  const int tid = threadIdx.x;
  const int w = tid >> 6, lane = tid & 63, q = lane >> 4, l15 = lane & 15;

  __shared__ __attribute__((aligned(16))) unsigned short tile[2][16][648];

  short8 wfr[2][20];
#pragma unroll
  for (int ct = 0; ct < 2; ++ct)
#pragma unroll
    for (int kt = 0; kt < 20; ++kt)
      wfr[ct][kt] = *(const short8*)(WcT +
                                     (size_t)(32 * w + 16 * ct + l15) * 640 +
                                     kt * 32 + q * 8);
  float4v bv[2];
#pragma unroll
  for (int ct = 0; ct < 2; ++ct)
    bv[ct] = *(const float4v*)(bc + 32 * w + 16 * ct + 4 * q);

  float4v mx[2];
  mx[0] = (float4v){-1e30f, -1e30f, -1e30f, -1e30f};
  mx[1] = mx[0];

  const int srow = tid >> 4, ssub = tid & 15;
  {
    const unsigned short* src = x + ((size_t)(b0 + srow) * T_ + t0) * 640;
#pragma unroll
    for (int j = 0; j < 5; ++j)
      *(short8*)&tile[0][srow][ssub * 8 + j * 128] =
          *(const short8*)(src + ssub * 8 + j * 128);
  }
  __syncthreads();

#pragma unroll 1
  for (int j = 0; j < 16; ++j) {
    const int t = t0 + j;
    const int buf = j & 1;
    if (j < 15) {
      const unsigned short* src = x + ((size_t)(b0 + srow) * T_ + t + 1) * 640;
#pragma unroll
      for (int jj = 0; jj < 5; ++jj)
        *(short8*)&tile[buf ^ 1][srow][ssub * 8 + jj * 128] =
            *(const short8*)(src + ssub * 8 + jj * 128);
    }
    float4v acc[2];
    acc[0] = (float4v){0.f, 0.f, 0.f, 0.f};
    acc[1] = (float4v){0.f, 0.f, 0.f, 0.f};
#pragma unroll
    for (int kt = 0; kt < 20; ++kt) {
      int row, so1, so2;
      if (kt < 8) {
        row = 2 * kt + (q >> 1);
        so1 = 64 * (2 * (q & 1)) + 4 * l15;
        so2 = so1 + 64;
      } else if (kt < 12) {
        row = 2 * (kt - 8) + (q >> 1) + 8 * (q & 1);
        so1 = 256 + 4 * l15;
        so2 = 320 + 4 * l15;
      } else {
        row = 2 * (kt - 12) + (q >> 1);
        so1 = 384 + 64 * (2 * (q & 1)) + 4 * l15;
        so2 = so1 + 64;
      }
      union { unsigned u[4]; short8 s; } cv;
      uint2v c1 = *(const uint2v*)&tile[buf][row][so1];
      uint2v c2 = *(const uint2v*)&tile[buf][row][so2];
      cv.u[0] = c1.x; cv.u[1] = c1.y; cv.u[2] = c2.x; cv.u[3] = c2.y;
      acc[0] = __builtin_amdgcn_mfma_f32_16x16x32_bf16(wfr[0][kt], cv.s,
                                                       acc[0], 0, 0, 0);
      acc[1] = __builtin_amdgcn_mfma_f32_16x16x32_bf16(wfr[1][kt], cv.s,
                                                       acc[1], 0, 0, 0);
    }
#pragma unroll
    for (int ct = 0; ct < 2; ++ct)
#pragma unroll
      for (int i = 0; i < 4; ++i)
        mx[ct][i] = fmaxf(mx[ct][i], acc[ct][i]);  // pre-activation max
    __syncthreads();
  }
#pragma unroll
  for (int ct = 0; ct < 2; ++ct)
#pragma unroll
    for (int i = 0; i < 4; ++i)
      atomicMax(pooled + (b0 + l15) * C_ + 32 * w + 16 * ct + 4 * q + i,
                enc_f(fast_tanh(mx[ct][i] + bv[ct][i])));
}

// ---------------------------------------------------------------------------
// dense: out = sigmoid(pooled @ Wd + bd)  [256,128]@[128,2]
// ---------------------------------------------------------------------------
__global__ __launch_bounds__(256) void dense_kernel(
    const unsigned int* __restrict__ pooled, const float* __restrict__ Wd,
    const float* __restrict__ bd, float* __restrict__ out) {
  int b = threadIdx.x;
  float s0 = bd[0], s1 = bd[1];
#pragma unroll 4
  for (int c = 0; c < C_; ++c) {
    float f = dec_f(pooled[b * C_ + c]);
    s0 += f * Wd[c * 2 + 0];
    s1 += f * Wd[c * 2 + 1];
  }
  out[b * 2 + 0] = 1.f / (1.f + __expf(-s0));
  out[b * 2 + 1] = 1.f / (1.f + __expf(-s1));
}

// ---------------------------------------------------------------------------
extern "C" void kernel_launch(void* const* d_in, const int* in_sizes, int n_in,
                              void* d_out, int out_size, void* d_ws, size_t ws_size,
                              hipStream_t stream) {
  const int* idxC = (const int*)d_in[0];
  const int* idxL = (const int*)d_in[1];
  const int* idxR = (const int*)d_in[2];
  const float* emb = (const float*)d_in[3];
  const float* Wf = (const float*)d_in[4];
  const float* Uf = (const float*)d_in[5];
  const float* bf_ = (const float*)d_in[6];
  const float* Wb = (const float*)d_in[7];
  const float* Ub = (const float*)d_in[8];
  const float* bb_ = (const float*)d_in[9];
  const float* Wc = (const float*)d_in[10];
  const float* bc = (const float*)d_in[11];
  const float* Wd = (const float*)d_in[12];
  const float* bd = (const float*)d_in[13];

  char* ws = (char*)d_ws;
  unsigned short* x = (unsigned short*)ws;                          // 167,772,160 B
  unsigned int* pooled = (unsigned int*)(ws + 167772160);           //     131,072 B
  unsigned short* WfT = (unsigned short*)(ws + 167903232);          //      65,536 B
  unsigned short* WbT = WfT + 256 * 128;
  unsigned short* WcT = WbT + 256 * 128;
  unsigned short* UfT = WcT + 128 * 640;
  unsigned short* UbT = UfT + 256 * 256;
  int* flags = (int*)(ws + 168460288);                              //       4,096 B

  prep_kernel<<<64, 256, 0, stream>>>(Wf, Wb, Wc, Uf, Ub, WfT, WbT, WcT, UfT,
                                      UbT, pooled, flags);
  fused_kernel<<<1568, 512, 120 * 1024, stream>>>(idxL, idxR, idxC, emb, WfT,
                                                  WbT, bf_, bb_, UfT, UbT, x,
                                                  flags);
  convpool_kernel<<<512, 256, 0, stream>>>(x, WcT, bc, pooled);
  dense_kernel<<<1, 256, 0, stream>>>(pooled, Wd, bd, (float*)d_out);
}